// Round 1
// baseline (289.438 us; speedup 1.0000x reference)
//
#include <hip/hip_runtime.h>
#include <math.h>

#define BB 8
#define CC 1024
#define HW 48
#define NN 2304   // 48*48
#define MM 2304
#define KK 32
#define CG 32

// ---------------- Kernel 1: antialiased linear resize 384->48, threshold > 0.5 ----------------
__global__ void mask_kernel(const float* __restrict__ rm, float* __restrict__ mask) {
    int t = blockIdx.x * 256 + threadIdx.x;
    if (t >= BB * NN) return;
    int b = t / NN, p = t % NN;
    int y = p / HW, x = p % HW;
    const float* src = rm + (size_t)b * 384 * 384;

    int jx0 = 8 * x - 4;
    float wx[16];
    float wxs = 0.f;
    #pragma unroll
    for (int dx = 0; dx < 16; ++dx) {
        int jx = jx0 + dx;
        float w = 1.0f - fabsf((float)dx - 7.5f) * 0.125f;  // triangle, scale 8
        if (jx >= 0 && jx < 384) { wx[dx] = w; wxs += w; } else wx[dx] = 0.f;
    }
    int jy0 = 8 * y - 4;
    float acc = 0.f, wys = 0.f;
    for (int dy = 0; dy < 16; ++dy) {
        int jy = jy0 + dy;
        if (jy < 0 || jy >= 384) continue;
        float wy = 1.0f - fabsf((float)dy - 7.5f) * 0.125f;
        wys += wy;
        const float* row = src + (size_t)jy * 384;
        float rs = 0.f;
        #pragma unroll
        for (int dx = 0; dx < 16; ++dx) {
            if (wx[dx] > 0.f) rs += wx[dx] * row[jx0 + dx];
        }
        acc += wy * rs;
    }
    float v = acc / (wys * wxs);
    mask[t] = (v > 0.5f) ? 1.0f : 0.0f;
}

// ---------------- Kernel 2: scores[b,n] = sum_m corr[b,n,m]*mask[b,m] ----------------
// one wave (64 lanes) per row; 4 rows per 256-thread block
__global__ void scores_kernel(const float* __restrict__ corr, const float* __restrict__ mask,
                              float* __restrict__ scores) {
    int wave = threadIdx.x >> 6, lane = threadIdx.x & 63;
    int row = blockIdx.x * 4 + wave;           // [0, BB*NN)
    int b = row / NN, n = row % NN;
    const float4* cr = (const float4*)(corr + ((size_t)b * NN + n) * MM);
    const float4* mr = (const float4*)(mask + (size_t)b * MM);
    float acc = 0.f;
    #pragma unroll
    for (int it = 0; it < 9; ++it) {           // 2304/4 = 576 = 64*9
        int i = it * 64 + lane;
        float4 cv = cr[i];
        float4 mv = mr[i];
        acc += cv.x * mv.x + cv.y * mv.y + cv.z * mv.z + cv.w * mv.w;
    }
    #pragma unroll
    for (int off = 32; off >= 1; off >>= 1) acc += __shfl_down(acc, off);
    if (lane == 0) scores[row] = acc;
}

// ---------------- Kernel 3: top-K per batch (descending, tie -> lower index) ----------------
__global__ void topk_kernel(const float* __restrict__ scores, int* __restrict__ idxo) {
    __shared__ float s[NN];
    __shared__ float rv[256];
    __shared__ int   ri[256];
    int b = blockIdx.x, t = threadIdx.x;
    for (int j = t; j < NN; j += 256) s[j] = scores[b * NN + j];
    __syncthreads();
    for (int it = 0; it < KK; ++it) {
        float bv = -INFINITY; int bi = 0;
        for (int j = t; j < NN; j += 256) {     // ascending j -> lowest index on ties
            float v = s[j];
            if (v > bv) { bv = v; bi = j; }
        }
        rv[t] = bv; ri[t] = bi;
        __syncthreads();
        for (int off = 128; off >= 1; off >>= 1) {
            if (t < off) {
                float ov = rv[t + off]; int oi = ri[t + off];
                if (ov > rv[t] || (ov == rv[t] && oi < ri[t])) { rv[t] = ov; ri[t] = oi; }
            }
            __syncthreads();
        }
        if (t == 0) { idxo[b * KK + it] = ri[0]; s[ri[0]] = -INFINITY; }
        __syncthreads();
    }
}

// ---------------- Kernel 4: gather struct[b,k,c] = cur[b,c,idx[b,k]] ----------------
__global__ void gather_kernel(const float* __restrict__ cur, const int* __restrict__ idx,
                              float* __restrict__ st) {
    int t = blockIdx.x * 256 + threadIdx.x;     // b*K*C + k*C + c
    int c = t % CC; int bk = t / CC; int k = bk % KK; int b = bk / KK;
    int id = idx[b * KK + k];
    st[t] = cur[((size_t)b * CC + c) * NN + id];
}

// ---------------- Kernel 5: struct_info[b,k,n] = sum_c struct[b,k,c]*cur[b,c,n] ----------------
// block: one (b, 64-wide n tile); 256 threads: k = t/8, 8 n each
__global__ void si_kernel(const float* __restrict__ cur, const float* __restrict__ st,
                          float* __restrict__ si) {
    __shared__ float XL[32][64];
    __shared__ float SL[32][33];   // pad: avoid 8-way bank conflict on column read
    int blk = blockIdx.x; int b = blk / 36; int n0 = (blk % 36) * 64;
    int t = threadIdx.x; int k = t >> 3, cg = t & 7;
    float acc[8] = {0.f, 0.f, 0.f, 0.f, 0.f, 0.f, 0.f, 0.f};
    for (int c0 = 0; c0 < CC; c0 += 32) {
        #pragma unroll
        for (int q = 0; q < 8; ++q) {
            int e = t + q * 256; int i = e >> 6, nn = e & 63;
            XL[i][nn] = cur[((size_t)b * CC + c0 + i) * NN + n0 + nn];
        }
        #pragma unroll
        for (int q = 0; q < 4; ++q) {
            int e = t + q * 256; int kk = e >> 5, cc2 = e & 31;
            SL[kk][cc2] = st[((size_t)b * KK + kk) * CC + c0 + cc2];
        }
        __syncthreads();
        #pragma unroll
        for (int cc2 = 0; cc2 < 32; ++cc2) {
            float sv = SL[k][cc2];
            const float* xr = &XL[cc2][cg * 8];
            #pragma unroll
            for (int j = 0; j < 8; ++j) acc[j] += sv * xr[j];
        }
        __syncthreads();
    }
    #pragma unroll
    for (int j = 0; j < 8; ++j)
        si[((size_t)b * KK + k) * NN + n0 + cg * 8 + j] = acc[j];
}

// ---------------- Kernel 6: fused grouped conv + global conv + weighting + concat ----------------
// block: one (b, 64-wide n tile); 256 threads: o = t/8 (0..31), 8 n each
__global__ void out_kernel(const float* __restrict__ cur, const float* __restrict__ si,
                           const float* __restrict__ gw, const float* __restrict__ gb,
                           const float* __restrict__ glw, const float* __restrict__ glb,
                           float* __restrict__ out) {
    __shared__ float XL[32][64];
    __shared__ float WL[32][33];
    __shared__ float GL[32][33];
    __shared__ float SIL[32][64];
    __shared__ float MS[64];
    int blk = blockIdx.x; int b = blk / 36; int n0 = (blk % 36) * 64;
    int t = threadIdx.x; int o = t >> 3, cg = t & 7;

    #pragma unroll
    for (int q = 0; q < 8; ++q) {
        int e = t + q * 256; int kk = e >> 6, nn = e & 63;
        SIL[kk][nn] = si[((size_t)b * KK + kk) * NN + n0 + nn];
    }
    __syncthreads();
    if (t < 64) {
        float s = 0.f;
        #pragma unroll
        for (int kk = 0; kk < 32; ++kk) s += SIL[kk][t];
        MS[t] = s * (1.0f / 32.0f);
    }

    float accg[8] = {0.f, 0.f, 0.f, 0.f, 0.f, 0.f, 0.f, 0.f};
    float accl[8] = {0.f, 0.f, 0.f, 0.f, 0.f, 0.f, 0.f, 0.f};
    for (int k = 0; k < KK; ++k) {
        __syncthreads();   // previous-iter readers done before restaging
        #pragma unroll
        for (int q = 0; q < 8; ++q) {
            int e = t + q * 256; int i = e >> 6, nn = e & 63;
            XL[i][nn] = cur[((size_t)b * CC + k * 32 + i) * NN + n0 + nn];
        }
        #pragma unroll
        for (int q = 0; q < 4; ++q) {
            int e = t + q * 256; int o2 = e >> 5, i = e & 31;
            WL[o2][i] = gw[k * 1024 + e];              // gw[k][o][i]
            GL[o2][i] = glw[o2 * CC + k * 32 + i];     // glw[o][c]
        }
        __syncthreads();
        float tmp[8] = {0.f, 0.f, 0.f, 0.f, 0.f, 0.f, 0.f, 0.f};
        #pragma unroll 8
        for (int i = 0; i < 32; ++i) {
            float w = WL[o][i];
            float g = GL[o][i];
            const float* xr = &XL[i][cg * 8];
            #pragma unroll
            for (int j = 0; j < 8; ++j) {
                float xv = xr[j];
                tmp[j]  += w * xv;
                accl[j] += g * xv;
            }
        }
        float bias = gb[k * 32 + o];
        #pragma unroll
        for (int j = 0; j < 8; ++j)
            accg[j] += SIL[k][cg * 8 + j] * fmaxf(tmp[j] + bias, 0.0f);
    }
    size_t ob = (size_t)b * 64 * NN;
    float gbias = glb[o];
    #pragma unroll
    for (int j = 0; j < 8; ++j) {
        int nn = cg * 8 + j;
        out[ob + (size_t)o * NN + n0 + nn] = accg[j];
        out[ob + (size_t)(32 + o) * NN + n0 + nn] = fmaxf(accl[j] + gbias, 0.0f) * MS[nn];
    }
}

extern "C" void kernel_launch(void* const* d_in, const int* in_sizes, int n_in,
                              void* d_out, int out_size, void* d_ws, size_t ws_size,
                              hipStream_t stream) {
    const float* corr = (const float*)d_in[0];   // [B,48,48,48,48]
    const float* cur  = (const float*)d_in[1];   // [B,1024,48,48]
    const float* rm   = (const float*)d_in[2];   // [B,1,384,384]
    const float* gw   = (const float*)d_in[3];   // [32,32,32]
    const float* gb   = (const float*)d_in[4];   // [1024]
    const float* glw  = (const float*)d_in[5];   // [32,1024]
    const float* glb  = (const float*)d_in[6];   // [32]
    float* out = (float*)d_out;
    float* ws  = (float*)d_ws;

    float* mask   = ws;                                  // B*M
    float* scores = ws + BB * MM;                        // B*N
    int*   idx    = (int*)(ws + BB * MM + BB * NN);      // B*K ints (256)
    float* st     = ws + BB * MM + BB * NN + 256;        // B*K*C
    float* si     = st + BB * KK * CC;                   // B*K*N

    mask_kernel<<<(BB * NN + 255) / 256, 256, 0, stream>>>(rm, mask);
    scores_kernel<<<BB * NN / 4, 256, 0, stream>>>(corr, mask, scores);
    topk_kernel<<<BB, 256, 0, stream>>>(scores, idx);
    gather_kernel<<<BB * KK * CC / 256, 256, 0, stream>>>(cur, idx, st);
    si_kernel<<<BB * (NN / 64), 256, 0, stream>>>(cur, st, si);
    out_kernel<<<BB * (NN / 64), 256, 0, stream>>>(cur, si, gw, gb, glw, glb, out);
}

// Round 2
// 217.602 us; speedup vs baseline: 1.3301x; 1.3301x over previous
//
#include <hip/hip_runtime.h>
#include <math.h>

#define BB 8
#define CC 1024
#define HW 48
#define NN 2304   // 48*48
#define MM 2304
#define KK 32
#define CG 32

// ---------------- Kernel 1: antialiased linear resize 384->48, threshold > 0.5 ----------------
__global__ void mask_kernel(const float* __restrict__ rm, float* __restrict__ mask) {
    int t = blockIdx.x * 256 + threadIdx.x;
    if (t >= BB * NN) return;
    int b = t / NN, p = t % NN;
    int y = p / HW, x = p % HW;
    const float* src = rm + (size_t)b * 384 * 384;

    int jx0 = 8 * x - 4;
    float wx[16];
    float wxs = 0.f;
    #pragma unroll
    for (int dx = 0; dx < 16; ++dx) {
        int jx = jx0 + dx;
        float w = 1.0f - fabsf((float)dx - 7.5f) * 0.125f;  // triangle, scale 8
        if (jx >= 0 && jx < 384) { wx[dx] = w; wxs += w; } else wx[dx] = 0.f;
    }
    int jy0 = 8 * y - 4;
    float acc = 0.f, wys = 0.f;
    for (int dy = 0; dy < 16; ++dy) {
        int jy = jy0 + dy;
        if (jy < 0 || jy >= 384) continue;
        float wy = 1.0f - fabsf((float)dy - 7.5f) * 0.125f;
        wys += wy;
        const float* row = src + (size_t)jy * 384;
        float rs = 0.f;
        #pragma unroll
        for (int dx = 0; dx < 16; ++dx) {
            if (wx[dx] > 0.f) rs += wx[dx] * row[jx0 + dx];
        }
        acc += wy * rs;
    }
    float v = acc / (wys * wxs);
    mask[t] = (v > 0.5f) ? 1.0f : 0.0f;
}

// ---------------- Kernel 2: scores[b,n] = sum_m corr[b,n,m]*mask[b,m] ----------------
__global__ void scores_kernel(const float* __restrict__ corr, const float* __restrict__ mask,
                              float* __restrict__ scores) {
    int wave = threadIdx.x >> 6, lane = threadIdx.x & 63;
    int row = blockIdx.x * 4 + wave;           // [0, BB*NN)
    int b = row / NN, n = row % NN;
    const float4* cr = (const float4*)(corr + ((size_t)b * NN + n) * MM);
    const float4* mr = (const float4*)(mask + (size_t)b * MM);
    float acc = 0.f;
    #pragma unroll
    for (int it = 0; it < 9; ++it) {           // 2304/4 = 576 = 64*9
        int i = it * 64 + lane;
        float4 cv = cr[i];
        float4 mv = mr[i];
        acc += cv.x * mv.x + cv.y * mv.y + cv.z * mv.z + cv.w * mv.w;
    }
    #pragma unroll
    for (int off = 32; off >= 1; off >>= 1) acc += __shfl_down(acc, off);
    if (lane == 0) scores[row] = acc;
}

// ---------------- Kernel 3: top-K per batch (descending, tie -> lower index) ----------------
__global__ void topk_kernel(const float* __restrict__ scores, int* __restrict__ idxo) {
    __shared__ float s[NN];
    __shared__ float wv[4];
    __shared__ int   wi[4];
    int b = blockIdx.x, t = threadIdx.x;
    for (int j = t; j < NN; j += 256) s[j] = scores[b * NN + j];
    __syncthreads();
    for (int it = 0; it < KK; ++it) {
        float bv = -INFINITY; int bi = NN;
        for (int j = t; j < NN; j += 256) {     // ascending j -> lowest index on ties
            float v = s[j];
            if (v > bv) { bv = v; bi = j; }
        }
        #pragma unroll
        for (int off = 32; off >= 1; off >>= 1) {
            float ov = __shfl_down(bv, off);
            int   oi = __shfl_down(bi, off);
            if (ov > bv || (ov == bv && oi < bi)) { bv = ov; bi = oi; }
        }
        if ((t & 63) == 0) { wv[t >> 6] = bv; wi[t >> 6] = bi; }
        __syncthreads();
        if (t == 0) {
            #pragma unroll
            for (int w = 1; w < 4; ++w)
                if (wv[w] > bv || (wv[w] == bv && wi[w] < bi)) { bv = wv[w]; bi = wi[w]; }
            idxo[b * KK + it] = bi;
            s[bi] = -INFINITY;
        }
        __syncthreads();
    }
}

// ---------------- Kernel 4: gather struct[b,k,c] = cur[b,c,idx[b,k]] ----------------
__global__ void gather_kernel(const float* __restrict__ cur, const int* __restrict__ idx,
                              float* __restrict__ st) {
    int t = blockIdx.x * 256 + threadIdx.x;     // b*K*C + k*C + c
    int c = t % CC; int bk = t / CC; int k = bk % KK; int b = bk / KK;
    int id = idx[b * KK + k];
    st[t] = cur[((size_t)b * CC + c) * NN + id];
}

// ---------------- Kernel 5 (fused): si + grouped conv + global conv + concat ----------------
// grid: 8 * 72 blocks, 256 threads. Per block: (b, 32-wide n tile).
// Phase 1: si[k][n] = sum_c st[k][c]*cur[c][n]   (k = t>>3, 4 n per thread)
// Phase 2: k-loop over groups: grouped conv + global conv, weighted by si.
// Double-buffered LDS staging with async split (load -> compute -> ds_write -> barrier).
__global__ __launch_bounds__(256) void fused_kernel(const float* __restrict__ cur,
                            const float* __restrict__ st, const float* __restrict__ gw,
                            const float* __restrict__ gb, const float* __restrict__ glw,
                            const float* __restrict__ glb, float* __restrict__ out) {
    __shared__ __align__(16) float XL[2][32][32];   // cur chunk [c-in-chunk][n]
    __shared__ float AW[2][32][36];                 // phase1: st chunk [k][c]; phase2: gw [o][i]
    __shared__ float GL[2][32][36];                 // phase2: glw [o][i]
    __shared__ __align__(16) float SIL[32][32];     // si [k][n]
    __shared__ float MS[32];                        // mean over k of si
    __shared__ float GB[CC];                        // group bias

    int blk = blockIdx.x; int b = blk / 72; int n0 = (blk % 72) * 32;
    int t = threadIdx.x; int r = t >> 3, q = t & 7;   // r: k/o index; q: float4 of n

    const float* curb = cur + ((size_t)b * CC) * NN + n0 + q * 4;
    const float* stb  = st + ((size_t)b * KK + r) * CC + q * 4;

    // stage group bias once
    #pragma unroll
    for (int u = 0; u < 4; ++u) GB[t + u * 256] = gb[t + u * 256];

    // ---------------- phase 1: si ----------------
    {
        float4 x = *(const float4*)(curb + (size_t)r * NN);
        float4 s = *(const float4*)(stb);
        *(float4*)&XL[0][r][q * 4] = x;
        AW[0][r][q * 4 + 0] = s.x; AW[0][r][q * 4 + 1] = s.y;
        AW[0][r][q * 4 + 2] = s.z; AW[0][r][q * 4 + 3] = s.w;
    }
    __syncthreads();
    float4 acc = {0.f, 0.f, 0.f, 0.f};
    for (int c = 0; c < 32; ++c) {
        int buf = c & 1;
        float4 px, ps;
        if (c < 31) {
            px = *(const float4*)(curb + (size_t)((c + 1) * 32 + r) * NN);
            ps = *(const float4*)(stb + (c + 1) * 32);
        }
        #pragma unroll
        for (int i = 0; i < 32; ++i) {
            float sv = AW[buf][r][i];
            float4 x = *(const float4*)&XL[buf][i][q * 4];
            acc.x += sv * x.x; acc.y += sv * x.y; acc.z += sv * x.z; acc.w += sv * x.w;
        }
        if (c < 31) {
            *(float4*)&XL[buf ^ 1][r][q * 4] = px;
            AW[buf ^ 1][r][q * 4 + 0] = ps.x; AW[buf ^ 1][r][q * 4 + 1] = ps.y;
            AW[buf ^ 1][r][q * 4 + 2] = ps.z; AW[buf ^ 1][r][q * 4 + 3] = ps.w;
        }
        __syncthreads();
    }
    *(float4*)&SIL[r][q * 4] = acc;
    __syncthreads();
    if (t < 32) {
        float s = 0.f;
        #pragma unroll
        for (int k = 0; k < 32; ++k) s += SIL[k][t];
        MS[t] = s * (1.0f / 32.0f);
    }

    // ---------------- phase 2: epilogue ----------------
    {
        float4 x = *(const float4*)(curb + (size_t)r * NN);
        float4 w = *(const float4*)(gw + t * 4);
        float4 g = *(const float4*)(glw + (size_t)r * CC + q * 4);
        *(float4*)&XL[0][r][q * 4] = x;
        AW[0][r][q * 4 + 0] = w.x; AW[0][r][q * 4 + 1] = w.y;
        AW[0][r][q * 4 + 2] = w.z; AW[0][r][q * 4 + 3] = w.w;
        GL[0][r][q * 4 + 0] = g.x; GL[0][r][q * 4 + 1] = g.y;
        GL[0][r][q * 4 + 2] = g.z; GL[0][r][q * 4 + 3] = g.w;
    }
    __syncthreads();
    float4 accg = {0.f, 0.f, 0.f, 0.f};
    float4 accl = {0.f, 0.f, 0.f, 0.f};
    for (int k = 0; k < 32; ++k) {
        int buf = k & 1;
        float4 px, pw, pg;
        if (k < 31) {
            px = *(const float4*)(curb + (size_t)((k + 1) * 32 + r) * NN);
            pw = *(const float4*)(gw + (k + 1) * 1024 + t * 4);
            pg = *(const float4*)(glw + (size_t)r * CC + (k + 1) * 32 + q * 4);
        }
        float bias = GB[k * 32 + r];
        float4 tmp = {0.f, 0.f, 0.f, 0.f};
        #pragma unroll
        for (int i = 0; i < 32; ++i) {
            float w = AW[buf][r][i];
            float g = GL[buf][r][i];
            float4 x = *(const float4*)&XL[buf][i][q * 4];
            tmp.x += w * x.x;  tmp.y += w * x.y;  tmp.z += w * x.z;  tmp.w += w * x.w;
            accl.x += g * x.x; accl.y += g * x.y; accl.z += g * x.z; accl.w += g * x.w;
        }
        float4 sv = *(const float4*)&SIL[k][q * 4];
        accg.x += sv.x * fmaxf(tmp.x + bias, 0.f);
        accg.y += sv.y * fmaxf(tmp.y + bias, 0.f);
        accg.z += sv.z * fmaxf(tmp.z + bias, 0.f);
        accg.w += sv.w * fmaxf(tmp.w + bias, 0.f);
        if (k < 31) {
            *(float4*)&XL[buf ^ 1][r][q * 4] = px;
            AW[buf ^ 1][r][q * 4 + 0] = pw.x; AW[buf ^ 1][r][q * 4 + 1] = pw.y;
            AW[buf ^ 1][r][q * 4 + 2] = pw.z; AW[buf ^ 1][r][q * 4 + 3] = pw.w;
            GL[buf ^ 1][r][q * 4 + 0] = pg.x; GL[buf ^ 1][r][q * 4 + 1] = pg.y;
            GL[buf ^ 1][r][q * 4 + 2] = pg.z; GL[buf ^ 1][r][q * 4 + 3] = pg.w;
        }
        __syncthreads();
    }
    // epilogue write
    size_t ob = (size_t)b * 64 * NN;
    float gbias = glb[r];
    float4 ol;
    ol.x = fmaxf(accl.x + gbias, 0.f) * MS[q * 4 + 0];
    ol.y = fmaxf(accl.y + gbias, 0.f) * MS[q * 4 + 1];
    ol.z = fmaxf(accl.z + gbias, 0.f) * MS[q * 4 + 2];
    ol.w = fmaxf(accl.w + gbias, 0.f) * MS[q * 4 + 3];
    *(float4*)(out + ob + (size_t)r * NN + n0 + q * 4) = accg;
    *(float4*)(out + ob + (size_t)(32 + r) * NN + n0 + q * 4) = ol;
}

extern "C" void kernel_launch(void* const* d_in, const int* in_sizes, int n_in,
                              void* d_out, int out_size, void* d_ws, size_t ws_size,
                              hipStream_t stream) {
    const float* corr = (const float*)d_in[0];   // [B,48,48,48,48]
    const float* cur  = (const float*)d_in[1];   // [B,1024,48,48]
    const float* rm   = (const float*)d_in[2];   // [B,1,384,384]
    const float* gw   = (const float*)d_in[3];   // [32,32,32]
    const float* gb   = (const float*)d_in[4];   // [1024]
    const float* glw  = (const float*)d_in[5];   // [32,1024]
    const float* glb  = (const float*)d_in[6];   // [32]
    float* out = (float*)d_out;
    float* ws  = (float*)d_ws;

    float* mask   = ws;                                  // B*M
    float* scores = ws + BB * MM;                        // B*N
    int*   idx    = (int*)(ws + BB * MM + BB * NN);      // B*K ints (256)
    float* st     = ws + BB * MM + BB * NN + 256;        // B*K*C

    mask_kernel<<<(BB * NN + 255) / 256, 256, 0, stream>>>(rm, mask);
    scores_kernel<<<BB * NN / 4, 256, 0, stream>>>(corr, mask, scores);
    topk_kernel<<<BB, 256, 0, stream>>>(scores, idx);
    gather_kernel<<<BB * KK * CC / 256, 256, 0, stream>>>(cur, idx, st);
    fused_kernel<<<BB * (NN / 32), 256, 0, stream>>>(cur, st, gw, gb, glw, glb, out);
}

// Round 3
// 172.683 us; speedup vs baseline: 1.6761x; 1.2601x over previous
//
#include <hip/hip_runtime.h>
#include <math.h>

#define BB 8
#define CC 1024
#define HW 48
#define NN 2304   // 48*48
#define MM 2304
#define KK 32

typedef __attribute__((ext_vector_type(8))) short short8v;
typedef __attribute__((ext_vector_type(4))) float f32x4;

__device__ __forceinline__ unsigned short f2bf(float f) {
    unsigned u = __float_as_uint(f);
    return (unsigned short)((u + 0x7FFFu + ((u >> 16) & 1u)) >> 16);
}

__device__ __forceinline__ void gll16(const unsigned short* g, unsigned short* l) {
    __builtin_amdgcn_global_load_lds(
        (const __attribute__((address_space(1))) void*)g,
        (__attribute__((address_space(3))) void*)l, 16, 0, 0);
}

// ---------------- Kernel 1: antialiased linear resize 384->48, threshold > 0.5 ----------------
__global__ void mask_kernel(const float* __restrict__ rm, float* __restrict__ mask) {
    int t = blockIdx.x * 256 + threadIdx.x;
    if (t >= BB * NN) return;
    int b = t / NN, p = t % NN;
    int y = p / HW, x = p % HW;
    const float* src = rm + (size_t)b * 384 * 384;

    int jx0 = 8 * x - 4;
    float wx[16];
    float wxs = 0.f;
    #pragma unroll
    for (int dx = 0; dx < 16; ++dx) {
        int jx = jx0 + dx;
        float w = 1.0f - fabsf((float)dx - 7.5f) * 0.125f;
        if (jx >= 0 && jx < 384) { wx[dx] = w; wxs += w; } else wx[dx] = 0.f;
    }
    int jy0 = 8 * y - 4;
    float acc = 0.f, wys = 0.f;
    for (int dy = 0; dy < 16; ++dy) {
        int jy = jy0 + dy;
        if (jy < 0 || jy >= 384) continue;
        float wy = 1.0f - fabsf((float)dy - 7.5f) * 0.125f;
        wys += wy;
        const float* row = src + (size_t)jy * 384;
        float rs = 0.f;
        #pragma unroll
        for (int dx = 0; dx < 16; ++dx) {
            if (wx[dx] > 0.f) rs += wx[dx] * row[jx0 + dx];
        }
        acc += wy * rs;
    }
    float v = acc / (wys * wxs);
    mask[t] = (v > 0.5f) ? 1.0f : 0.0f;
}

// ---------------- Kernel 2: scores[b,n] = sum_m corr[b,n,m]*mask[b,m] ----------------
__global__ void scores_kernel(const float* __restrict__ corr, const float* __restrict__ mask,
                              float* __restrict__ scores) {
    int wave = threadIdx.x >> 6, lane = threadIdx.x & 63;
    int row = blockIdx.x * 4 + wave;
    int b = row / NN, n = row % NN;
    const float4* cr = (const float4*)(corr + ((size_t)b * NN + n) * MM);
    const float4* mr = (const float4*)(mask + (size_t)b * MM);
    float acc = 0.f;
    #pragma unroll
    for (int it = 0; it < 9; ++it) {
        int i = it * 64 + lane;
        float4 cv = cr[i];
        float4 mv = mr[i];
        acc += cv.x * mv.x + cv.y * mv.y + cv.z * mv.z + cv.w * mv.w;
    }
    #pragma unroll
    for (int off = 32; off >= 1; off >>= 1) acc += __shfl_down(acc, off);
    if (lane == 0) scores[row] = acc;
}

// ---------------- Kernel 3a: per-chunk top-32 (8 chunks of 288 per batch) ----------------
__global__ void topk1_kernel(const float* __restrict__ scores,
                             float* __restrict__ cval, int* __restrict__ cidx) {
    int b = blockIdx.x >> 3, ch = blockIdx.x & 7;
    int t = threadIdx.x;
    const float* s = scores + b * NN + ch * 288;
    float v0 = s[t];
    float v1 = (t < 32) ? s[256 + t] : -INFINITY;
    int i0 = t, i1 = 256 + t;
    __shared__ float wv[4]; __shared__ int wi[4];
    __shared__ float bwv; __shared__ int bwi;
    for (int it = 0; it < KK; ++it) {
        float bv = (v0 >= v1) ? v0 : v1;   // i0 < i1 always -> tie keeps lower index
        int   bi = (v0 >= v1) ? i0 : i1;
        #pragma unroll
        for (int off = 32; off >= 1; off >>= 1) {
            float ov = __shfl_down(bv, off);
            int   oi = __shfl_down(bi, off);
            if (ov > bv || (ov == bv && oi < bi)) { bv = ov; bi = oi; }
        }
        if ((t & 63) == 0) { wv[t >> 6] = bv; wi[t >> 6] = bi; }
        __syncthreads();
        if (t == 0) {
            #pragma unroll
            for (int u = 1; u < 4; ++u)
                if (wv[u] > bv || (wv[u] == bv && wi[u] < bi)) { bv = wv[u]; bi = wi[u]; }
            bwv = bv; bwi = bi;
            cval[(b * 8 + ch) * 32 + it] = bv;
            cidx[(b * 8 + ch) * 32 + it] = ch * 288 + bi;
        }
        __syncthreads();
        int W = bwi;
        if (i0 == W) v0 = -INFINITY;
        if (i1 == W) v1 = -INFINITY;
    }
}

// ---------------- Kernel 3b: merge 256 candidates -> top-32 per batch ----------------
__global__ void topk2_kernel(const float* __restrict__ cval, const int* __restrict__ cidx,
                             int* __restrict__ idxo) {
    int b = blockIdx.x, t = threadIdx.x;
    float v = cval[b * 256 + t];
    int gi = cidx[b * 256 + t];
    __shared__ float wv[4]; __shared__ int wi[4];
    __shared__ int bwi_s;
    for (int it = 0; it < KK; ++it) {
        float bv = v; int bi = gi;
        #pragma unroll
        for (int off = 32; off >= 1; off >>= 1) {
            float ov = __shfl_down(bv, off);
            int   oi = __shfl_down(bi, off);
            if (ov > bv || (ov == bv && oi < bi)) { bv = ov; bi = oi; }
        }
        if ((t & 63) == 0) { wv[t >> 6] = bv; wi[t >> 6] = bi; }
        __syncthreads();
        if (t == 0) {
            #pragma unroll
            for (int u = 1; u < 4; ++u)
                if (wv[u] > bv || (wv[u] == bv && wi[u] < bi)) { bv = wv[u]; bi = wi[u]; }
            idxo[b * KK + it] = bi;
            bwi_s = bi;
        }
        __syncthreads();
        if (gi == bwi_s) v = -INFINITY;
    }
}

// ---------------- Kernel 4: gather struct (bf16) ----------------
__global__ void gather_kernel(const float* __restrict__ cur, const int* __restrict__ idx,
                              unsigned short* __restrict__ st) {
    int t = blockIdx.x * 256 + threadIdx.x;
    int c = t & (CC - 1); int bk = t >> 10; int k = bk & 31; int b = bk >> 5;
    int id = idx[b * KK + k];
    st[t] = f2bf(cur[((size_t)b * CC + c) * NN + id]);
}

// ---------------- Kernel 5: weights -> bf16 ----------------
__global__ void wconv_kernel(const float* __restrict__ gw, const float* __restrict__ glw,
                             unsigned short* __restrict__ gwh, unsigned short* __restrict__ glwh) {
    int t = blockIdx.x * 256 + threadIdx.x;   // 32768 each
    gwh[t] = f2bf(gw[t]);
    glwh[t] = f2bf(glw[t]);
}

// ---------------- Kernel 6: fused MFMA si + grouped conv + global conv + concat ----------------
// grid 8*72 blocks (b, 32-n tile), 256 threads = 4 waves, wave w owns 16x16 tile (m=w>>1, nt=w&1)
__global__ __launch_bounds__(256) void fused_mfma(
    const float* __restrict__ cur, const unsigned short* __restrict__ st16,
    const unsigned short* __restrict__ gwh, const unsigned short* __restrict__ glwh,
    const float* __restrict__ gb, const float* __restrict__ glb,
    float* __restrict__ out)
{
    __shared__ unsigned short XT[2][1024];   // [n][c] bf16, 64B rows (X^T chunk)
    __shared__ unsigned short AC[2][1024];   // pass A: st chunk [k][c]; pass B: gw_k [o][i]
    __shared__ unsigned short GC[2][1024];   // glw chunk [o][c]
    __shared__ float SIL[32][33];
    __shared__ float GBL[CC];
    __shared__ float MS[32];
    __shared__ float GLBL[32];

    int blk = blockIdx.x;
    int b = blk / 72, n0 = (blk % 72) * 32;
    int t = threadIdx.x;
    int w = t >> 6, l = t & 63;
    int m = w >> 1, nt = w & 1;

    for (int i = t; i < CC; i += 256) GBL[i] = gb[i];
    if (t < 32) GLBL[t] = glb[t];

    const float* curb = cur + (size_t)b * CC * NN;
    const unsigned short* stb = st16 + b * (KK * CC);

    int ci = t >> 3, ns = t & 7;   // for t<128: c-pair, n-quad
    const float* xsrc0 = curb + (size_t)(2 * ci) * NN + n0 + 4 * ns;
    const float* xsrc1 = xsrc0 + NN;

    // frag offsets (elements)
    int fro = (16 * m + (l & 15)) * 32 + 8 * (l >> 4);
    int fxo = (16 * nt + (l & 15)) * 32 + 8 * (l >> 4);

    // ---- pass A prologue: stage chunk 0 into buf 0 ----
    if (t < 128) {
        float4 f0 = *(const float4*)(xsrc0);
        float4 f1 = *(const float4*)(xsrc1);
        unsigned pk;
        pk = (unsigned)f2bf(f0.x) | ((unsigned)f2bf(f1.x) << 16); *(unsigned*)&XT[0][(4*ns+0)*32 + 2*ci] = pk;
        pk = (unsigned)f2bf(f0.y) | ((unsigned)f2bf(f1.y) << 16); *(unsigned*)&XT[0][(4*ns+1)*32 + 2*ci] = pk;
        pk = (unsigned)f2bf(f0.z) | ((unsigned)f2bf(f1.z) << 16); *(unsigned*)&XT[0][(4*ns+2)*32 + 2*ci] = pk;
        pk = (unsigned)f2bf(f0.w) | ((unsigned)f2bf(f1.w) << 16); *(unsigned*)&XT[0][(4*ns+3)*32 + 2*ci] = pk;
    } else if (w == 2) {
        gll16(stb + (l >> 2) * CC + (l & 3) * 8, &AC[0][0]);
        gll16(stb + (16 + (l >> 2)) * CC + (l & 3) * 8, &AC[0][512]);
    } else {
        gll16(glwh + (l >> 2) * CC + (l & 3) * 8, &GC[0][0]);
        gll16(glwh + (16 + (l >> 2)) * CC + (l & 3) * 8, &GC[0][512]);
    }
    __syncthreads();

    // ---- pass A: si (st x X) and global conv (glw x X), K=1024 ----
    f32x4 siacc = {0.f, 0.f, 0.f, 0.f};
    f32x4 glacc = {0.f, 0.f, 0.f, 0.f};
    for (int cc = 0; cc < 32; ++cc) {
        int buf = cc & 1;
        bool stg = (cc < 31);
        float4 f0, f1;
        if (stg) {
            if (t < 128) {
                f0 = *(const float4*)(xsrc0 + (size_t)(cc + 1) * 32 * NN);
                f1 = *(const float4*)(xsrc1 + (size_t)(cc + 1) * 32 * NN);
            } else if (w == 2) {
                gll16(stb + (l >> 2) * CC + (cc + 1) * 32 + (l & 3) * 8, &AC[buf ^ 1][0]);
                gll16(stb + (16 + (l >> 2)) * CC + (cc + 1) * 32 + (l & 3) * 8, &AC[buf ^ 1][512]);
            } else {
                gll16(glwh + (l >> 2) * CC + (cc + 1) * 32 + (l & 3) * 8, &GC[buf ^ 1][0]);
                gll16(glwh + (16 + (l >> 2)) * CC + (cc + 1) * 32 + (l & 3) * 8, &GC[buf ^ 1][512]);
            }
        }
        short8v ast = *(const short8v*)&AC[buf][fro];
        short8v agl = *(const short8v*)&GC[buf][fro];
        short8v bx  = *(const short8v*)&XT[buf][fxo];
        siacc = __builtin_amdgcn_mfma_f32_16x16x32_bf16(ast, bx, siacc, 0, 0, 0);
        glacc = __builtin_amdgcn_mfma_f32_16x16x32_bf16(agl, bx, glacc, 0, 0, 0);
        if (stg && t < 128) {
            int bo = buf ^ 1;
            unsigned pk;
            pk = (unsigned)f2bf(f0.x) | ((unsigned)f2bf(f1.x) << 16); *(unsigned*)&XT[bo][(4*ns+0)*32 + 2*ci] = pk;
            pk = (unsigned)f2bf(f0.y) | ((unsigned)f2bf(f1.y) << 16); *(unsigned*)&XT[bo][(4*ns+1)*32 + 2*ci] = pk;
            pk = (unsigned)f2bf(f0.z) | ((unsigned)f2bf(f1.z) << 16); *(unsigned*)&XT[bo][(4*ns+2)*32 + 2*ci] = pk;
            pk = (unsigned)f2bf(f0.w) | ((unsigned)f2bf(f1.w) << 16); *(unsigned*)&XT[bo][(4*ns+3)*32 + 2*ci] = pk;
        }
        __syncthreads();
    }

    // si -> LDS
    #pragma unroll
    for (int r = 0; r < 4; ++r)
        SIL[16 * m + 4 * (l >> 4) + r][16 * nt + (l & 15)] = siacc[r];
    __syncthreads();
    if (t < 32) {
        float s = 0.f;
        #pragma unroll
        for (int k = 0; k < 32; ++k) s += SIL[k][t];
        MS[t] = s * (1.0f / 32.0f);
    }

    // ---- pass B prologue: stage chunk 0 + W_0 ----
    if (t < 128) {
        float4 f0 = *(const float4*)(xsrc0);
        float4 f1 = *(const float4*)(xsrc1);
        unsigned pk;
        pk = (unsigned)f2bf(f0.x) | ((unsigned)f2bf(f1.x) << 16); *(unsigned*)&XT[0][(4*ns+0)*32 + 2*ci] = pk;
        pk = (unsigned)f2bf(f0.y) | ((unsigned)f2bf(f1.y) << 16); *(unsigned*)&XT[0][(4*ns+1)*32 + 2*ci] = pk;
        pk = (unsigned)f2bf(f0.z) | ((unsigned)f2bf(f1.z) << 16); *(unsigned*)&XT[0][(4*ns+2)*32 + 2*ci] = pk;
        pk = (unsigned)f2bf(f0.w) | ((unsigned)f2bf(f1.w) << 16); *(unsigned*)&XT[0][(4*ns+3)*32 + 2*ci] = pk;
    } else if (w == 2) {
        gll16(gwh + l * 8, &AC[0][0]);
        gll16(gwh + 512 + l * 8, &AC[0][512]);
    }
    __syncthreads();

    // ---- pass B: grouped conv + relu + si-weighting ----
    f32x4 accg = {0.f, 0.f, 0.f, 0.f};
    const f32x4 zz = {0.f, 0.f, 0.f, 0.f};
    for (int k = 0; k < 32; ++k) {
        int buf = k & 1;
        bool stg = (k < 31);
        float4 f0, f1;
        if (stg) {
            if (t < 128) {
                f0 = *(const float4*)(xsrc0 + (size_t)(k + 1) * 32 * NN);
                f1 = *(const float4*)(xsrc1 + (size_t)(k + 1) * 32 * NN);
            } else if (w == 2) {
                gll16(gwh + (k + 1) * 1024 + l * 8, &AC[buf ^ 1][0]);
                gll16(gwh + (k + 1) * 1024 + 512 + l * 8, &AC[buf ^ 1][512]);
            }
        }
        short8v aw = *(const short8v*)&AC[buf][fro];
        short8v bx = *(const short8v*)&XT[buf][fxo];
        f32x4 gf = __builtin_amdgcn_mfma_f32_16x16x32_bf16(aw, bx, zz, 0, 0, 0);
        float sik = SIL[k][16 * nt + (l & 15)];
        #pragma unroll
        for (int r = 0; r < 4; ++r) {
            int orow = 16 * m + 4 * (l >> 4) + r;
            accg[r] += sik * fmaxf(gf[r] + GBL[k * 32 + orow], 0.f);
        }
        if (stg && t < 128) {
            int bo = buf ^ 1;
            unsigned pk;
            pk = (unsigned)f2bf(f0.x) | ((unsigned)f2bf(f1.x) << 16); *(unsigned*)&XT[bo][(4*ns+0)*32 + 2*ci] = pk;
            pk = (unsigned)f2bf(f0.y) | ((unsigned)f2bf(f1.y) << 16); *(unsigned*)&XT[bo][(4*ns+1)*32 + 2*ci] = pk;
            pk = (unsigned)f2bf(f0.z) | ((unsigned)f2bf(f1.z) << 16); *(unsigned*)&XT[bo][(4*ns+2)*32 + 2*ci] = pk;
            pk = (unsigned)f2bf(f0.w) | ((unsigned)f2bf(f1.w) << 16); *(unsigned*)&XT[bo][(4*ns+3)*32 + 2*ci] = pk;
        }
        __syncthreads();
    }

    // ---- write out ----
    int col = 16 * nt + (l & 15);
    size_t ob = (size_t)b * 64 * NN + n0 + col;
    float msv = MS[col];
    #pragma unroll
    for (int r = 0; r < 4; ++r) {
        int orow = 16 * m + 4 * (l >> 4) + r;
        out[ob + (size_t)orow * NN] = accg[r];
        out[ob + (size_t)(32 + orow) * NN] = fmaxf(glacc[r] + GLBL[orow], 0.f) * msv;
    }
}

extern "C" void kernel_launch(void* const* d_in, const int* in_sizes, int n_in,
                              void* d_out, int out_size, void* d_ws, size_t ws_size,
                              hipStream_t stream) {
    const float* corr = (const float*)d_in[0];   // [B,48,48,48,48]
    const float* cur  = (const float*)d_in[1];   // [B,1024,48,48]
    const float* rm   = (const float*)d_in[2];   // [B,1,384,384]
    const float* gw   = (const float*)d_in[3];   // [32,32,32]
    const float* gb   = (const float*)d_in[4];   // [1024]
    const float* glw  = (const float*)d_in[5];   // [32,1024]
    const float* glb  = (const float*)d_in[6];   // [32]
    float* out = (float*)d_out;
    float* ws  = (float*)d_ws;

    float* mask   = ws;                                   // 18432 f32
    float* scores = mask + BB * MM;                       // 18432 f32
    float* cval   = scores + BB * NN;                     // 2048 f32
    int*   cidx   = (int*)(cval + 2048);                  // 2048 i32
    int*   idx    = cidx + 2048;                          // 256 i32
    unsigned short* st16 = (unsigned short*)(idx + 256);  // 262144 u16
    unsigned short* gwh  = st16 + BB * KK * CC;           // 32768 u16
    unsigned short* glwh = gwh + 32768;                   // 32768 u16

    mask_kernel<<<(BB * NN + 255) / 256, 256, 0, stream>>>(rm, mask);
    scores_kernel<<<BB * NN / 4, 256, 0, stream>>>(corr, mask, scores);
    topk1_kernel<<<BB * 8, 256, 0, stream>>>(scores, cval, cidx);
    topk2_kernel<<<BB, 256, 0, stream>>>(cval, cidx, idx);
    gather_kernel<<<BB * KK * CC / 256, 256, 0, stream>>>(cur, idx, st16);
    wconv_kernel<<<128, 256, 0, stream>>>(gw, glw, gwh, glwh);
    fused_mfma<<<BB * (NN / 32), 256, 0, stream>>>(cur, st16, gwh, glwh, gb, glb, out);
}

// Round 4
// 164.976 us; speedup vs baseline: 1.7544x; 1.0467x over previous
//
#include <hip/hip_runtime.h>
#include <math.h>

#define BB 8
#define CC 1024
#define HW 48
#define NN 2304   // 48*48
#define MM 2304
#define KK 32

typedef __attribute__((ext_vector_type(8))) short short8v;
typedef __attribute__((ext_vector_type(4))) float f32x4;

__device__ __forceinline__ unsigned short f2bf(float f) {
    unsigned u = __float_as_uint(f);
    return (unsigned short)((u + 0x7FFFu + ((u >> 16) & 1u)) >> 16);
}

// ---------------- Kernel 1: antialiased linear resize 384->48, threshold > 0.5 ----------------
__global__ void mask_kernel(const float* __restrict__ rm, float* __restrict__ mask) {
    int t = blockIdx.x * 256 + threadIdx.x;
    if (t >= BB * NN) return;
    int b = t / NN, p = t % NN;
    int y = p / HW, x = p % HW;
    const float* src = rm + (size_t)b * 384 * 384;

    int jx0 = 8 * x - 4;
    float wx[16];
    float wxs = 0.f;
    #pragma unroll
    for (int dx = 0; dx < 16; ++dx) {
        int jx = jx0 + dx;
        float w = 1.0f - fabsf((float)dx - 7.5f) * 0.125f;
        if (jx >= 0 && jx < 384) { wx[dx] = w; wxs += w; } else wx[dx] = 0.f;
    }
    int jy0 = 8 * y - 4;
    float acc = 0.f, wys = 0.f;
    for (int dy = 0; dy < 16; ++dy) {
        int jy = jy0 + dy;
        if (jy < 0 || jy >= 384) continue;
        float wy = 1.0f - fabsf((float)dy - 7.5f) * 0.125f;
        wys += wy;
        const float* row = src + (size_t)jy * 384;
        float rs = 0.f;
        #pragma unroll
        for (int dx = 0; dx < 16; ++dx) {
            if (wx[dx] > 0.f) rs += wx[dx] * row[jx0 + dx];
        }
        acc += wy * rs;
    }
    float v = acc / (wys * wxs);
    mask[t] = (v > 0.5f) ? 1.0f : 0.0f;
}

// ---------------- Kernel 2: scores[b,n] = sum_m corr[b,n,m]*mask[b,m] ----------------
__global__ void scores_kernel(const float* __restrict__ corr, const float* __restrict__ mask,
                              float* __restrict__ scores) {
    int wave = threadIdx.x >> 6, lane = threadIdx.x & 63;
    int row = blockIdx.x * 4 + wave;
    int b = row / NN, n = row % NN;
    const float4* cr = (const float4*)(corr + ((size_t)b * NN + n) * MM);
    const float4* mr = (const float4*)(mask + (size_t)b * MM);
    float acc = 0.f;
    #pragma unroll
    for (int it = 0; it < 9; ++it) {
        int i = it * 64 + lane;
        float4 cv = cr[i];
        float4 mv = mr[i];
        acc += cv.x * mv.x + cv.y * mv.y + cv.z * mv.z + cv.w * mv.w;
    }
    #pragma unroll
    for (int off = 32; off >= 1; off >>= 1) acc += __shfl_down(acc, off);
    if (lane == 0) scores[row] = acc;
}

// ---------------- Kernel 3a: per-chunk top-32 (8 chunks of 288 per batch) ----------------
__global__ void topk1_kernel(const float* __restrict__ scores,
                             float* __restrict__ cval, int* __restrict__ cidx) {
    int b = blockIdx.x >> 3, ch = blockIdx.x & 7;
    int t = threadIdx.x;
    const float* s = scores + b * NN + ch * 288;
    float v0 = s[t];
    float v1 = (t < 32) ? s[256 + t] : -INFINITY;
    int i0 = t, i1 = 256 + t;
    __shared__ float wv[4]; __shared__ int wi[4];
    __shared__ int bwi;
    for (int it = 0; it < KK; ++it) {
        float bv = (v0 >= v1) ? v0 : v1;   // i0 < i1 always -> tie keeps lower index
        int   bi = (v0 >= v1) ? i0 : i1;
        #pragma unroll
        for (int off = 32; off >= 1; off >>= 1) {
            float ov = __shfl_down(bv, off);
            int   oi = __shfl_down(bi, off);
            if (ov > bv || (ov == bv && oi < bi)) { bv = ov; bi = oi; }
        }
        if ((t & 63) == 0) { wv[t >> 6] = bv; wi[t >> 6] = bi; }
        __syncthreads();
        if (t == 0) {
            #pragma unroll
            for (int u = 1; u < 4; ++u)
                if (wv[u] > bv || (wv[u] == bv && wi[u] < bi)) { bv = wv[u]; bi = wi[u]; }
            bwi = bi;
            cval[(b * 8 + ch) * 32 + it] = bv;
            cidx[(b * 8 + ch) * 32 + it] = ch * 288 + bi;
        }
        __syncthreads();
        int W = bwi;
        if (i0 == W) v0 = -INFINITY;
        if (i1 == W) v1 = -INFINITY;
    }
}

// ---------------- Kernel 3b: merge 256 candidates -> top-32 per batch ----------------
__global__ void topk2_kernel(const float* __restrict__ cval, const int* __restrict__ cidx,
                             int* __restrict__ idxo) {
    int b = blockIdx.x, t = threadIdx.x;
    float v = cval[b * 256 + t];
    int gi = cidx[b * 256 + t];
    __shared__ float wv[4]; __shared__ int wi[4];
    __shared__ int bwi_s;
    for (int it = 0; it < KK; ++it) {
        float bv = v; int bi = gi;
        #pragma unroll
        for (int off = 32; off >= 1; off >>= 1) {
            float ov = __shfl_down(bv, off);
            int   oi = __shfl_down(bi, off);
            if (ov > bv || (ov == bv && oi < bi)) { bv = ov; bi = oi; }
        }
        if ((t & 63) == 0) { wv[t >> 6] = bv; wi[t >> 6] = bi; }
        __syncthreads();
        if (t == 0) {
            #pragma unroll
            for (int u = 1; u < 4; ++u)
                if (wv[u] > bv || (wv[u] == bv && wi[u] < bi)) { bv = wv[u]; bi = wi[u]; }
            idxo[b * KK + it] = bi;
            bwi_s = bi;
        }
        __syncthreads();
        if (gi == bwi_s) v = -INFINITY;
    }
}

// ---------------- Kernel 4: gather struct (bf16) ----------------
__global__ void gather_kernel(const float* __restrict__ cur, const int* __restrict__ idx,
                              unsigned short* __restrict__ st) {
    int t = blockIdx.x * 256 + threadIdx.x;
    int c = t & (CC - 1); int bk = t >> 10; int k = bk & 31; int b = bk >> 5;
    int id = idx[b * KK + k];
    st[t] = f2bf(cur[((size_t)b * CC + c) * NN + id]);
}

// ---------------- Kernel 5: weights -> bf16 ----------------
__global__ void wconv_kernel(const float* __restrict__ gw, const float* __restrict__ glw,
                             unsigned short* __restrict__ gwh, unsigned short* __restrict__ glwh) {
    int t = blockIdx.x * 256 + threadIdx.x;   // 32768 each
    gwh[t] = f2bf(gw[t]);
    glwh[t] = f2bf(glw[t]);
}

// ---------------- Kernel 6: fused MFMA, stage-once structure ----------------
// grid 8*144 (XCD-chunked: b = hw&7, tile = hw>>3), 256 thr = 4 waves.
// XT[16 n][1024 c] bf16 staged ONCE (swizzled). Pass A: wave w -> (mat=w>>1: st|glw,
// mrow=w&1) 16x16 tile over K=1024, A-frags straight from global (L2-hot).
// Pass B: wave w owns groups k=8w..8w+7, partial tiles reduced via LDS.
__global__ __launch_bounds__(256) void fused_mfma(
    const float* __restrict__ cur, const unsigned short* __restrict__ st16,
    const unsigned short* __restrict__ gwh, const unsigned short* __restrict__ glwh,
    const float* __restrict__ gb, const float* __restrict__ glb,
    float* __restrict__ out)
{
    __shared__ unsigned short XT[16 * 1024];   // 32KB, row n: 2048B, slot16 ^= (n&7)
    __shared__ float SIL[32][18];
    __shared__ float PART[4][2][256];
    __shared__ float MS[16];
    __shared__ float GBL[CC];
    __shared__ float GLBL[32];

    int hw = blockIdx.x;
    int b = hw & 7;                 // XCD-chunked: XCD j owns batch j
    int n0 = (hw >> 3) * 16;
    int t = threadIdx.x;
    int w = t >> 6, l = t & 63;
    int mrow = w & 1, mat = w >> 1;
    int nrow = l & 15, kq = l >> 4;

    for (int i = t; i < CC; i += 256) GBL[i] = gb[i];
    if (t < 32) GLBL[t] = glb[t];

    // ---- stage XT once: 16 independent float4 loads per thread ----
    const float* curb = cur + (size_t)b * CC * NN;
    int nq = t & 3, ci0 = t >> 2;
    #pragma unroll
    for (int q = 0; q < 8; ++q) {
        int ci = ci0 + 64 * q;                 // c-pair 0..511
        int c = 2 * ci;
        const float* p0 = curb + (size_t)c * NN + n0 + 4 * nq;
        float4 f0 = *(const float4*)p0;
        float4 f1 = *(const float4*)(p0 + NN);
        float a0[4] = {f0.x, f0.y, f0.z, f0.w};
        float a1[4] = {f1.x, f1.y, f1.z, f1.w};
        #pragma unroll
        for (int r = 0; r < 4; ++r) {
            int n = 4 * nq + r;
            unsigned pk = (unsigned)f2bf(a0[r]) | ((unsigned)f2bf(a1[r]) << 16);
            *(unsigned*)((char*)XT + n * 2048 + ((((ci >> 2) ^ (n & 7)) << 4) + ((ci & 3) << 2))) = pk;
        }
    }
    __syncthreads();

    // ---- pass A: per-wave independent 16x16 x K=1024 ----
    const char* xbase = (const char*)XT + nrow * 2048;
    const unsigned short* Abase = (mat == 0 ? st16 + (size_t)b * KK * CC : glwh)
                                  + (size_t)(16 * mrow + nrow) * CC + 8 * kq;
    f32x4 acc = {0.f, 0.f, 0.f, 0.f};
    #pragma unroll 8
    for (int cc = 0; cc < 32; ++cc) {
        short8v A = *(const short8v*)(Abase + cc * 32);
        short8v B = *(const short8v*)(xbase + (((cc * 4 + kq) ^ (nrow & 7)) << 4));
        acc = __builtin_amdgcn_mfma_f32_16x16x32_bf16(A, B, acc, 0, 0, 0);
    }

    if (mat == 0) {
        #pragma unroll
        for (int r = 0; r < 4; ++r)
            SIL[16 * mrow + 4 * kq + r][nrow] = acc[r];
    }
    __syncthreads();
    if (t < 16) {
        float s = 0.f;
        #pragma unroll
        for (int k = 0; k < 32; ++k) s += SIL[k][t];
        MS[t] = s * (1.0f / 32.0f);
    }

    // ---- pass B: grouped conv, 8 groups per wave ----
    f32x4 p0 = {0.f, 0.f, 0.f, 0.f}, p1 = {0.f, 0.f, 0.f, 0.f};
    const f32x4 zz = {0.f, 0.f, 0.f, 0.f};
    #pragma unroll
    for (int j = 0; j < 8; ++j) {
        int k = 8 * w + j;
        const unsigned short* gk = gwh + k * 1024 + 8 * kq;
        short8v A0 = *(const short8v*)(gk + nrow * 32);
        short8v A1 = *(const short8v*)(gk + (16 + nrow) * 32);
        short8v B = *(const short8v*)(xbase + (((k * 4 + kq) ^ (nrow & 7)) << 4));
        f32x4 g0 = __builtin_amdgcn_mfma_f32_16x16x32_bf16(A0, B, zz, 0, 0, 0);
        f32x4 g1 = __builtin_amdgcn_mfma_f32_16x16x32_bf16(A1, B, zz, 0, 0, 0);
        float sik = SIL[k][nrow];
        #pragma unroll
        for (int r = 0; r < 4; ++r) {
            p0[r] += sik * fmaxf(g0[r] + GBL[k * 32 + 4 * kq + r], 0.f);
            p1[r] += sik * fmaxf(g1[r] + GBL[k * 32 + 16 + 4 * kq + r], 0.f);
        }
    }
    *(f32x4*)&PART[w][0][l * 4] = p0;
    *(f32x4*)&PART[w][1][l * 4] = p1;
    __syncthreads();

    // ---- final writes ----
    size_t ob = (size_t)b * 64 * NN + n0 + nrow;
    if (mat == 0) {
        #pragma unroll
        for (int r = 0; r < 4; ++r) {
            int li = l * 4 + r;
            float v = PART[0][mrow][li] + PART[1][mrow][li]
                    + PART[2][mrow][li] + PART[3][mrow][li];
            out[ob + (size_t)(16 * mrow + 4 * kq + r) * NN] = v;
        }
    } else {
        float msv = MS[nrow];
        #pragma unroll
        for (int r = 0; r < 4; ++r) {
            int o = 16 * mrow + 4 * kq + r;
            out[ob + (size_t)(32 + o) * NN] = fmaxf(acc[r] + GLBL[o], 0.f) * msv;
        }
    }
}

extern "C" void kernel_launch(void* const* d_in, const int* in_sizes, int n_in,
                              void* d_out, int out_size, void* d_ws, size_t ws_size,
                              hipStream_t stream) {
    const float* corr = (const float*)d_in[0];   // [B,48,48,48,48]
    const float* cur  = (const float*)d_in[1];   // [B,1024,48,48]
    const float* rm   = (const float*)d_in[2];   // [B,1,384,384]
    const float* gw   = (const float*)d_in[3];   // [32,32,32]
    const float* gb   = (const float*)d_in[4];   // [1024]
    const float* glw  = (const float*)d_in[5];   // [32,1024]
    const float* glb  = (const float*)d_in[6];   // [32]
    float* out = (float*)d_out;
    float* ws  = (float*)d_ws;

    float* mask   = ws;                                   // 18432 f32
    float* scores = mask + BB * MM;                       // 18432 f32
    float* cval   = scores + BB * NN;                     // 2048 f32
    int*   cidx   = (int*)(cval + 2048);                  // 2048 i32
    int*   idx    = cidx + 2048;                          // 256 i32
    unsigned short* st16 = (unsigned short*)(idx + 256);  // 262144 u16
    unsigned short* gwh  = st16 + BB * KK * CC;           // 32768 u16
    unsigned short* glwh = gwh + 32768;                   // 32768 u16

    mask_kernel<<<(BB * NN + 255) / 256, 256, 0, stream>>>(rm, mask);
    scores_kernel<<<BB * NN / 4, 256, 0, stream>>>(corr, mask, scores);
    topk1_kernel<<<BB * 8, 256, 0, stream>>>(scores, cval, cidx);
    topk2_kernel<<<BB, 256, 0, stream>>>(cval, cidx, idx);
    gather_kernel<<<BB * KK * CC / 256, 256, 0, stream>>>(cur, idx, st16);
    wconv_kernel<<<128, 256, 0, stream>>>(gw, glw, gwh, glwh);
    fused_mfma<<<BB * (NN / 16), 256, 0, stream>>>(cur, st16, gwh, glwh, gb, glb, out);
}